// Round 14
// baseline (393.943 us; speedup 1.0000x reference)
//
#include <hip/hip_runtime.h>

#define NNODES 50000
#define MPAD   50048   // 391 * 128
#define NEDGES 600000
#define NGRAPHS 512
#define HID 128
#define NLAYERS 4
#define BN_EPS 1e-5f
#define GEMMBLK 391    // MPAD/128
#define PROWS 25       // pool rows per block: 50000/25 = 2000 blocks

typedef __bf16 bf16x8 __attribute__((ext_vector_type(8)));
typedef float  f32x4  __attribute__((ext_vector_type(4)));
typedef unsigned short u16x8 __attribute__((ext_vector_type(8)));

__device__ __forceinline__ unsigned short f2bf(float f) {
    unsigned u = __builtin_bit_cast(unsigned, f);
    unsigned r = (u + 0x7fffu + ((u >> 16) & 1u)) >> 16;
    return (unsigned short)r;
}
__device__ __forceinline__ float bf2f(unsigned short u) {
    return __builtin_bit_cast(float, (unsigned)u << 16);
}

// ---------------------------------------------------------------------------
// k_prep: one dispatch = split (6250 blocks) | wpack (64 blocks) | init (502)
// init also zeroes per-layer BN accumulators psum/pqsum (4*128 floats each).
// ---------------------------------------------------------------------------
__global__ void k_prep(const float* __restrict__ x,
                       unsigned short* __restrict__ xhi, unsigned short* __restrict__ xlo,
                       const float* __restrict__ Wl, const float* __restrict__ Wr,
                       unsigned short* __restrict__ Wpk,
                       int* __restrict__ deg,
                       int* __restrict__ pa, int* __restrict__ pb,
                       int* __restrict__ pc, int* __restrict__ pd,
                       int* __restrict__ pooled, int* __restrict__ gcnt,
                       float* __restrict__ psum, float* __restrict__ pqsum) {
    int b = blockIdx.x;
    if (b < 6250) {
        // ---- split fp32 -> (hi,lo) bf16 pair ----
        int idx = b * 256 + threadIdx.x;   // float4 index
        float4 v = ((const float4*)x)[idx];
        ushort4 h, l;
        h.x = f2bf(v.x); l.x = f2bf(v.x - bf2f(h.x));
        h.y = f2bf(v.y); l.y = f2bf(v.y - bf2f(h.y));
        h.z = f2bf(v.z); l.z = f2bf(v.z - bf2f(h.z));
        h.w = f2bf(v.w); l.w = f2bf(v.w - bf2f(h.w));
        *(ushort4*)(xhi + (size_t)idx * 4) = h;
        *(ushort4*)(xlo + (size_t)idx * 4) = l;
    } else if (b < 6250 + 64) {
        // ---- W prepack: 4 (l,ks,nf) units per block, one per 64-lane group ----
        int ub = (b - 6250) * 4 + (threadIdx.x >> 6);   // 0..255
        int lane = threadIdx.x & 63;
        int nf = ub & 7, ks = (ub >> 3) & 7, l = ub >> 6;
        int n = nf * 16 + (lane & 15);
        int k = ks * 32 + (lane >> 4) * 8;
        const float* W = (k < 128) ? (Wl + (size_t)l * HID * HID)
                                   : (Wr + (size_t)l * HID * HID - 128);
        size_t base = ((((size_t)l * 64 + ks * 8 + nf) * 2) * 64 + lane) * 8;
        #pragma unroll
        for (int j = 0; j < 8; ++j) {
            float w = W[(size_t)n * 128 + k + j];
            unsigned short h = f2bf(w);
            unsigned short lo = f2bf(w - bf2f(h));
            Wpk[base + j] = h;
            Wpk[base + 512 + j] = lo;
        }
    } else {
        // ---- zero-init: deg | pads | pooled | gcnt | psum/pqsum ----
        int t = (b - 6314) * 256 + threadIdx.x;
        if (t < 50000) { deg[t] = 0; }
        int u = t - 50000;
        if (u >= 0 && u < 3072) { pa[u] = 0; pb[u] = 0; pc[u] = 0; pd[u] = 0; }
        int v = t - 53072;
        if (v >= 0 && v < 65536) pooled[v] = 0;
        int w = t - 118608;
        if (w >= 0 && w < 512) gcnt[w] = 0;
        int z = t - 119120;
        if (z >= 0 && z < NLAYERS * HID) { psum[z] = 0.f; pqsum[z] = 0.f; }
    }
}

// ---------------------------------------------------------------------------
// CSR build (hierarchical scan: known-good ~6us)
// ---------------------------------------------------------------------------
__global__ void k_count_deg(const int* __restrict__ dst, int* __restrict__ deg, int E) {
    int e = blockIdx.x * blockDim.x + threadIdx.x;
    if (e < E) atomicAdd(&deg[dst[e]], 1);
}

__global__ void k_scan1(const int* __restrict__ deg, int* __restrict__ exg,
                        int* __restrict__ bsum, int n) {
    __shared__ int s[512];
    int tid = threadIdx.x;
    int i = blockIdx.x * 512 + tid;
    int v = (i < n) ? deg[i] : 0;
    s[tid] = v;
    __syncthreads();
    for (int off = 1; off < 512; off <<= 1) {
        int t = (tid >= off) ? s[tid - off] : 0;
        __syncthreads();
        s[tid] += t;
        __syncthreads();
    }
    if (i < n) exg[i] = s[tid] - v;
    if (tid == 511) bsum[blockIdx.x] = s[511];
}

__global__ void k_scan2(int* __restrict__ bsum, int nb) {
    __shared__ int s[128];
    int tid = threadIdx.x;
    int v = (tid < nb) ? bsum[tid] : 0;
    s[tid] = v;
    __syncthreads();
    for (int off = 1; off < 128; off <<= 1) {
        int t = (tid >= off) ? s[tid - off] : 0;
        __syncthreads();
        s[tid] += t;
        __syncthreads();
    }
    if (tid < nb) bsum[tid] = s[tid] - v;
}

__global__ void k_scan3(const int* __restrict__ exg, const int* __restrict__ bsum,
                        const int* __restrict__ deg,
                        int* __restrict__ rowptr, int* __restrict__ cursor,
                        float* __restrict__ inv_deg, int n, int E) {
    int i = blockIdx.x * blockDim.x + threadIdx.x;
    if (i < n) {
        int r = exg[i] + bsum[i >> 9];
        rowptr[i] = r;
        cursor[i] = r;
        int d = deg[i];
        inv_deg[i] = 1.0f / (float)max(d, 1);
        if (i == 0) rowptr[n] = E;
    }
}

__global__ void k_fill_csr(const int* __restrict__ src, const int* __restrict__ dst,
                           int* __restrict__ cursor, int* __restrict__ csr_src, int E) {
    int e = blockIdx.x * blockDim.x + threadIdx.x;
    if (e < E) {
        int pos = atomicAdd(&cursor[dst[e]], 1);
        csr_src[pos] = src[e];
    }
}

// ---------------------------------------------------------------------------
// Mean aggregation v7: row-major gather, 4-deep ILP (16 edges in flight).
// ---------------------------------------------------------------------------
__global__ void k_aggregate7(const unsigned short* __restrict__ xhi,
                             const int* __restrict__ csr_src, const int* __restrict__ rowptr,
                             const float* __restrict__ inv_deg,
                             unsigned short* __restrict__ ahi, unsigned short* __restrict__ alo) {
    int lane = threadIdx.x & 63;
    int wid = threadIdx.x >> 6;
    int node = blockIdx.x * 4 + wid;   // grid exact: 12500
    int beg = rowptr[node];
    int deg = rowptr[node + 1] - beg;
    int eg = lane >> 4;                // edge slot 0..3
    int fo = (lane & 15) * 8;          // feature offset (8 bf16 = 16B)

    int idx_l = (lane < deg) ? csr_src[beg + lane] : 0;

    float a0[8] = {0,0,0,0,0,0,0,0};
    float a1[8] = {0,0,0,0,0,0,0,0};
    float a2[8] = {0,0,0,0,0,0,0,0};
    float a3[8] = {0,0,0,0,0,0,0,0};
    int dmax = min(deg, 64);
    for (int base = 0; base < dmax; base += 16) {
        int s0 = __shfl(idx_l, base + eg);
        int s1 = __shfl(idx_l, base + 4 + eg);
        int s2 = __shfl(idx_l, base + 8 + eg);
        int s3 = __shfl(idx_l, base + 12 + eg);
        if (base + eg < deg) {
            u16x8 v = *(const u16x8*)(xhi + (size_t)s0 * 128 + fo);
            #pragma unroll
            for (int j = 0; j < 8; ++j) a0[j] += bf2f(v[j]);
        }
        if (base + 4 + eg < deg) {
            u16x8 v = *(const u16x8*)(xhi + (size_t)s1 * 128 + fo);
            #pragma unroll
            for (int j = 0; j < 8; ++j) a1[j] += bf2f(v[j]);
        }
        if (base + 8 + eg < deg) {
            u16x8 v = *(const u16x8*)(xhi + (size_t)s2 * 128 + fo);
            #pragma unroll
            for (int j = 0; j < 8; ++j) a2[j] += bf2f(v[j]);
        }
        if (base + 12 + eg < deg) {
            u16x8 v = *(const u16x8*)(xhi + (size_t)s3 * 128 + fo);
            #pragma unroll
            for (int j = 0; j < 8; ++j) a3[j] += bf2f(v[j]);
        }
    }
    // rare tail: deg > 64
    for (int e = beg + 64 + eg; e < beg + deg; e += 4) {
        int s = csr_src[e];
        u16x8 v = *(const u16x8*)(xhi + (size_t)s * 128 + fo);
        #pragma unroll
        for (int j = 0; j < 8; ++j) a0[j] += bf2f(v[j]);
    }

    #pragma unroll
    for (int j = 0; j < 8; ++j) {
        float a = (a0[j] + a1[j]) + (a2[j] + a3[j]);
        a += __shfl_xor(a, 16);
        a += __shfl_xor(a, 32);
        a0[j] = a;
    }
    if (lane < 16) {
        float idg = inv_deg[node];
        u16x8 hv, lv;
        #pragma unroll
        for (int j = 0; j < 8; ++j) {
            float a = a0[j] * idg;
            unsigned short h = f2bf(a);
            hv[j] = h;
            lv[j] = f2bf(a - bf2f(h));
        }
        *(u16x8*)(ahi + (size_t)node * 128 + fo) = hv;
        *(u16x8*)(alo + (size_t)node * 128 + fo) = lv;
    }
}

// ---------------------------------------------------------------------------
// MFMA GEMM + fused BN stats: block partials atomically accumulated into
// per-layer psum[128]/pqsum[128] (zeroed once in k_prep).
// ---------------------------------------------------------------------------
__launch_bounds__(256) __global__
void k_mfma_gemm(const unsigned short* __restrict__ Ahi0, const unsigned short* __restrict__ Alo0,
                 const unsigned short* __restrict__ Ahi1, const unsigned short* __restrict__ Alo1,
                 const unsigned short* __restrict__ Wpk, const float* __restrict__ bl,
                 float* __restrict__ Hout,
                 float* __restrict__ psum, float* __restrict__ pqsum) {
    int wid = threadIdx.x >> 6;
    int lane = threadIdx.x & 63;
    int m0 = blockIdx.x * 128 + wid * 32;
    int r = lane & 15;
    int kg = lane >> 4;

    f32x4 acc[2][8];
    #pragma unroll
    for (int nf = 0; nf < 8; ++nf) {
        float b = bl[nf * 16 + r];
        acc[0][nf] = f32x4{b, b, b, b};
        acc[1][nf] = f32x4{b, b, b, b};
    }

    #pragma unroll
    for (int ks = 0; ks < 8; ++ks) {
        const unsigned short* hi = (ks < 4) ? Ahi0 : Ahi1;
        const unsigned short* lo = (ks < 4) ? Alo0 : Alo1;
        int kc = (ks & 3) * 32 + kg * 8;
        bf16x8 ah0 = *(const bf16x8*)(hi + (size_t)(m0 + r) * 128 + kc);
        bf16x8 al0 = *(const bf16x8*)(lo + (size_t)(m0 + r) * 128 + kc);
        bf16x8 ah1 = *(const bf16x8*)(hi + (size_t)(m0 + 16 + r) * 128 + kc);
        bf16x8 al1 = *(const bf16x8*)(lo + (size_t)(m0 + 16 + r) * 128 + kc);
        const unsigned short* wb = Wpk + (size_t)ks * 8192;
        #pragma unroll
        for (int nf = 0; nf < 8; ++nf) {
            bf16x8 bh = *(const bf16x8*)(wb + (size_t)nf * 1024 + lane * 8);
            bf16x8 bl2 = *(const bf16x8*)(wb + (size_t)nf * 1024 + 512 + lane * 8);
            acc[0][nf] = __builtin_amdgcn_mfma_f32_16x16x32_bf16(ah0, bh,  acc[0][nf], 0, 0, 0);
            acc[0][nf] = __builtin_amdgcn_mfma_f32_16x16x32_bf16(al0, bh,  acc[0][nf], 0, 0, 0);
            acc[0][nf] = __builtin_amdgcn_mfma_f32_16x16x32_bf16(ah0, bl2, acc[0][nf], 0, 0, 0);
            acc[1][nf] = __builtin_amdgcn_mfma_f32_16x16x32_bf16(ah1, bh,  acc[1][nf], 0, 0, 0);
            acc[1][nf] = __builtin_amdgcn_mfma_f32_16x16x32_bf16(al1, bh,  acc[1][nf], 0, 0, 0);
            acc[1][nf] = __builtin_amdgcn_mfma_f32_16x16x32_bf16(ah1, bl2, acc[1][nf], 0, 0, 0);
        }
    }

    // C/D layout: col = lane&15, row = (lane>>4)*4 + reg
    #pragma unroll
    for (int mf = 0; mf < 2; ++mf)
        #pragma unroll
        for (int nf = 0; nf < 8; ++nf)
            #pragma unroll
            for (int g = 0; g < 4; ++g)
                Hout[(size_t)(m0 + mf * 16 + kg * 4 + g) * 128 + nf * 16 + r] = acc[mf][nf][g];

    // fused BN partial stats: per-column sum / sumsq over this block's 128 rows
    __shared__ float ls[4][8][16];
    __shared__ float lq[4][8][16];
    #pragma unroll
    for (int nf = 0; nf < 8; ++nf) {
        float ss = 0.f, qq = 0.f;
        #pragma unroll
        for (int mf = 0; mf < 2; ++mf)
            #pragma unroll
            for (int g = 0; g < 4; ++g) {
                int row = m0 + mf * 16 + kg * 4 + g;
                float v = acc[mf][nf][g];
                float msk = (row < NNODES) ? 1.f : 0.f;
                ss += v * msk;
                qq += v * v * msk;
            }
        ss += __shfl_xor(ss, 16);
        ss += __shfl_xor(ss, 32);
        qq += __shfl_xor(qq, 16);
        qq += __shfl_xor(qq, 32);
        if (lane < 16) { ls[wid][nf][lane] = ss; lq[wid][nf][lane] = qq; }
    }
    __syncthreads();
    int t = threadIdx.x;
    if (t < 128) {   // column t partials -> device atomics (391 adds/addr)
        float ssum = ls[0][t >> 4][t & 15] + ls[1][t >> 4][t & 15]
                   + ls[2][t >> 4][t & 15] + ls[3][t >> 4][t & 15];
        float qsum = lq[0][t >> 4][t & 15] + lq[1][t >> 4][t & 15]
                   + lq[2][t >> 4][t & 15] + lq[3][t >> 4][t & 15];
        atomicAdd(&psum[t], ssum);
        atomicAdd(&pqsum[t], qsum);
    }
}

// ---------------------------------------------------------------------------
// BN + ReLU with in-block scale/shift finalize (psum/pqsum fully reduced by
// the preceding GEMM's atomics); writes next-layer activations as hi/lo bf16.
// ---------------------------------------------------------------------------
__global__ void k_bnrelu3(const float* __restrict__ h,
                          const float* __restrict__ psum, const float* __restrict__ pqsum,
                          const float* __restrict__ gamma, const float* __restrict__ beta,
                          unsigned short* __restrict__ xhi, unsigned short* __restrict__ xlo) {
    __shared__ float scaleS[128], shiftS[128];
    int t = threadIdx.x;
    if (t < 128) {
        float s = psum[t], q = pqsum[t];
        float inv_n = 1.0f / (float)NNODES;
        float mu = s * inv_n;
        float var = q * inv_n - mu * mu;
        float is = rsqrtf(var + BN_EPS);
        float g = gamma[t] * is;
        scaleS[t] = g;
        shiftS[t] = beta[t] - mu * g;
    }
    __syncthreads();
    int idx = blockIdx.x * 256 + t;   // float4 index; grid exact 6250
    int c0 = (idx & 31) * 4;
    float4 v = ((const float4*)h)[idx];
    v.x = fmaxf(v.x * scaleS[c0 + 0] + shiftS[c0 + 0], 0.f);
    v.y = fmaxf(v.y * scaleS[c0 + 1] + shiftS[c0 + 1], 0.f);
    v.z = fmaxf(v.z * scaleS[c0 + 2] + shiftS[c0 + 2], 0.f);
    v.w = fmaxf(v.w * scaleS[c0 + 3] + shiftS[c0 + 3], 0.f);
    ushort4 hh, ll;
    hh.x = f2bf(v.x); ll.x = f2bf(v.x - bf2f(hh.x));
    hh.y = f2bf(v.y); ll.y = f2bf(v.y - bf2f(hh.y));
    hh.z = f2bf(v.z); ll.z = f2bf(v.z - bf2f(hh.z));
    hh.w = f2bf(v.w); ll.w = f2bf(v.w - bf2f(hh.w));
    *(ushort4*)(xhi + (size_t)idx * 4) = hh;
    *(ushort4*)(xlo + (size_t)idx * 4) = ll;
}

// ---------------------------------------------------------------------------
// Segmented pooling (unchanged)
// ---------------------------------------------------------------------------
__global__ void k_pool_seg(const unsigned short* __restrict__ xhi,
                           const unsigned short* __restrict__ xlo,
                           const int* __restrict__ batch,
                           float* __restrict__ pooled, int* __restrict__ gcnt) {
    int t = threadIdx.x;           // 64
    int r0 = blockIdx.x * PROWS;   // grid 2000 exact
    float a0 = 0.f, a1 = 0.f;
    int cur = batch[r0];
    int seg = r0;
    for (int i = 0; i < PROWS; ++i) {
        int r = r0 + i;
        int g = batch[r];
        if (g != cur) {
            atomicAdd(&pooled[cur * 128 + 2 * t], a0);
            atomicAdd(&pooled[cur * 128 + 2 * t + 1], a1);
            if (t == 0) atomicAdd(&gcnt[cur], r - seg);
            a0 = a1 = 0.f; cur = g; seg = r;
        }
        unsigned uh = *(const unsigned*)(xhi + (size_t)r * 128 + 2 * t);
        unsigned ul = *(const unsigned*)(xlo + (size_t)r * 128 + 2 * t);
        a0 += bf2f((unsigned short)(uh & 0xffff)) + bf2f((unsigned short)(ul & 0xffff));
        a1 += bf2f((unsigned short)(uh >> 16)) + bf2f((unsigned short)(ul >> 16));
    }
    atomicAdd(&pooled[cur * 128 + 2 * t], a0);
    atomicAdd(&pooled[cur * 128 + 2 * t + 1], a1);
    if (t == 0) atomicAdd(&gcnt[cur], r0 + PROWS - seg);
}

// ---------------------------------------------------------------------------
// Classifier (unchanged)
// ---------------------------------------------------------------------------
__global__ void k_cls(const float* __restrict__ pooled, const int* __restrict__ gcnt,
                      const float* __restrict__ W1, const float* __restrict__ b1,
                      const float* __restrict__ W2, const float* __restrict__ b2,
                      float* __restrict__ out) {
    int g = blockIdx.x;
    int t = threadIdx.x;  // 64
    __shared__ float P[128];
    __shared__ float H1[64];
    float inv = 1.0f / (float)max(gcnt[g], 1);
    P[t] = pooled[g * 128 + t] * inv;
    P[t + 64] = pooled[g * 128 + 64 + t] * inv;
    __syncthreads();
    float a = b1[t];
    #pragma unroll 8
    for (int k = 0; k < 128; ++k) a += P[k] * W1[t * 128 + k];
    H1[t] = fmaxf(a, 0.f);
    __syncthreads();
    if (t < 10) {
        float a2 = b2[t];
        #pragma unroll 8
        for (int k = 0; k < 64; ++k) a2 += H1[k] * W2[t * 64 + k];
        out[g * 10 + t] = a2;
    }
}

// ---------------------------------------------------------------------------
// launch
// ---------------------------------------------------------------------------
extern "C" void kernel_launch(void* const* d_in, const int* in_sizes, int n_in,
                              void* d_out, int out_size, void* d_ws, size_t ws_size,
                              hipStream_t stream) {
    const float* x_in  = (const float*)d_in[0];
    const int*   ei    = (const int*)d_in[1];
    const int*   batch = (const int*)d_in[2];
    const float* Wl    = (const float*)d_in[3];
    const float* bl    = (const float*)d_in[4];
    const float* Wr    = (const float*)d_in[5];
    const float* gamma = (const float*)d_in[6];
    const float* beta  = (const float*)d_in[7];
    const float* W1    = (const float*)d_in[8];
    const float* b1    = (const float*)d_in[9];
    const float* W2    = (const float*)d_in[10];
    const float* b2    = (const float*)d_in[11];
    float* out = (float*)d_out;

    const int N = NNODES, E = NEDGES;
    const int* src = ei;
    const int* dst = ei + E;

    char* p = (char*)d_ws;
    auto alloc = [&](size_t bytes) {
        char* r = p;
        p += (bytes + 255) & ~(size_t)255;
        return r;
    };
    unsigned short* ahi = (unsigned short*)alloc((size_t)MPAD * HID * 2);
    unsigned short* alo = (unsigned short*)alloc((size_t)MPAD * HID * 2);
    unsigned short* xhi = (unsigned short*)alloc((size_t)MPAD * HID * 2);
    unsigned short* xlo = (unsigned short*)alloc((size_t)MPAD * HID * 2);
    float*  h        = (float*)alloc((size_t)MPAD * HID * 4);
    unsigned short* wpk = (unsigned short*)alloc((size_t)NLAYERS * 64 * 2 * 64 * 8 * 2);
    int*    deg      = (int*)alloc((size_t)N * 4);
    float*  inv_deg  = (float*)alloc((size_t)N * 4);
    int*    rowptr   = (int*)alloc((size_t)(N + 1) * 4);
    int*    cursor   = (int*)alloc((size_t)N * 4);
    int*    csr_src  = (int*)alloc((size_t)E * 4);
    int*    exg      = (int*)alloc((size_t)N * 4);
    int*    bsum     = (int*)alloc(512);
    float*  psum     = (float*)alloc((size_t)NLAYERS * HID * 4);
    float*  pqsum    = (float*)alloc((size_t)NLAYERS * HID * 4);
    float*  pooled   = (float*)alloc((size_t)NGRAPHS * HID * 4);
    int*    gcnt     = (int*)alloc((size_t)NGRAPHS * 4);

    // ---- prep: split + wpack + zero-init in one dispatch (6816 blocks) ----
    k_prep<<<6816, 256, 0, stream>>>(x_in, xhi, xlo, Wl, Wr, wpk, deg,
                                     (int*)(ahi + (size_t)N * HID), (int*)(alo + (size_t)N * HID),
                                     (int*)(xhi + (size_t)N * HID), (int*)(xlo + (size_t)N * HID),
                                     (int*)pooled, gcnt, psum, pqsum);

    // ---- CSR build: count -> hierarchical scan -> fill ----
    int eb = (E + 255) / 256;
    k_count_deg<<<eb, 256, 0, stream>>>(dst, deg, E);
    int nb = (N + 511) / 512;
    k_scan1<<<nb, 512, 0, stream>>>(deg, exg, bsum, N);
    k_scan2<<<1, 128, 0, stream>>>(bsum, nb);
    k_scan3<<<(N + 255) / 256, 256, 0, stream>>>(exg, bsum, deg, rowptr, cursor, inv_deg, N, E);
    k_fill_csr<<<eb, 256, 0, stream>>>(src, dst, cursor, csr_src, E);

    // ---- layers: aggregate -> gemm(+BN atomics) -> bnrelu(in-block finalize) ----
    for (int l = 0; l < NLAYERS; ++l) {
        k_aggregate7<<<N / 4, 256, 0, stream>>>(xhi, csr_src, rowptr, inv_deg, ahi, alo);
        k_mfma_gemm<<<GEMMBLK, 256, 0, stream>>>(ahi, alo, xhi, xlo,
                                                 wpk + (size_t)l * 65536,
                                                 bl + (size_t)l * HID, h,
                                                 psum + (size_t)l * HID,
                                                 pqsum + (size_t)l * HID);
        k_bnrelu3<<<(N * HID / 4) / 256, 256, 0, stream>>>(h,
                                                 psum + (size_t)l * HID,
                                                 pqsum + (size_t)l * HID,
                                                 gamma + (size_t)l * HID,
                                                 beta + (size_t)l * HID, xhi, xlo);
    }

    // ---- pool + classifier ----
    k_pool_seg<<<N / PROWS, 64, 0, stream>>>(xhi, xlo, batch, pooled, gcnt);
    k_cls<<<NGRAPHS, 64, 0, stream>>>(pooled, gcnt, W1, b1, W2, b2, out);
}

// Round 15
// 374.517 us; speedup vs baseline: 1.0519x; 1.0519x over previous
//
#include <hip/hip_runtime.h>

#define NNODES 50000
#define MPAD   50048   // 391 * 128
#define NEDGES 600000
#define NGRAPHS 512
#define HID 128
#define NLAYERS 4
#define BN_EPS 1e-5f
#define GEMMBLK 391    // MPAD/128
#define PROWS 25       // pool rows per block: 50000/25 = 2000 blocks

typedef __bf16 bf16x8 __attribute__((ext_vector_type(8)));
typedef float  f32x4  __attribute__((ext_vector_type(4)));
typedef unsigned short u16x8 __attribute__((ext_vector_type(8)));

__device__ __forceinline__ unsigned short f2bf(float f) {
    unsigned u = __builtin_bit_cast(unsigned, f);
    unsigned r = (u + 0x7fffu + ((u >> 16) & 1u)) >> 16;
    return (unsigned short)r;
}
__device__ __forceinline__ float bf2f(unsigned short u) {
    return __builtin_bit_cast(float, (unsigned)u << 16);
}

// ---------------------------------------------------------------------------
// k_prep: one dispatch = split (6250 blocks) | wpack (64 blocks) | init (502)
// ---------------------------------------------------------------------------
__global__ void k_prep(const float* __restrict__ x,
                       unsigned short* __restrict__ xhi, unsigned short* __restrict__ xlo,
                       const float* __restrict__ Wl, const float* __restrict__ Wr,
                       unsigned short* __restrict__ Wpk,
                       int* __restrict__ deg,
                       int* __restrict__ pa, int* __restrict__ pb,
                       int* __restrict__ pc, int* __restrict__ pd,
                       int* __restrict__ pooled, int* __restrict__ gcnt) {
    int b = blockIdx.x;
    if (b < 6250) {
        // ---- split fp32 -> (hi,lo) bf16 pair ----
        int idx = b * 256 + threadIdx.x;   // float4 index
        float4 v = ((const float4*)x)[idx];
        ushort4 h, l;
        h.x = f2bf(v.x); l.x = f2bf(v.x - bf2f(h.x));
        h.y = f2bf(v.y); l.y = f2bf(v.y - bf2f(h.y));
        h.z = f2bf(v.z); l.z = f2bf(v.z - bf2f(h.z));
        h.w = f2bf(v.w); l.w = f2bf(v.w - bf2f(h.w));
        *(ushort4*)(xhi + (size_t)idx * 4) = h;
        *(ushort4*)(xlo + (size_t)idx * 4) = l;
    } else if (b < 6250 + 64) {
        // ---- W prepack: 4 (l,ks,nf) units per block, one per 64-lane group ----
        int ub = (b - 6250) * 4 + (threadIdx.x >> 6);   // 0..255
        int lane = threadIdx.x & 63;
        int nf = ub & 7, ks = (ub >> 3) & 7, l = ub >> 6;
        int n = nf * 16 + (lane & 15);
        int k = ks * 32 + (lane >> 4) * 8;
        const float* W = (k < 128) ? (Wl + (size_t)l * HID * HID)
                                   : (Wr + (size_t)l * HID * HID - 128);
        size_t base = ((((size_t)l * 64 + ks * 8 + nf) * 2) * 64 + lane) * 8;
        #pragma unroll
        for (int j = 0; j < 8; ++j) {
            float w = W[(size_t)n * 128 + k + j];
            unsigned short h = f2bf(w);
            unsigned short lo = f2bf(w - bf2f(h));
            Wpk[base + j] = h;
            Wpk[base + 512 + j] = lo;
        }
    } else {
        // ---- zero-init: deg | pads | pooled | gcnt ----
        int t = (b - 6314) * 256 + threadIdx.x;
        if (t < 50000) { deg[t] = 0; }
        int u = t - 50000;
        if (u >= 0 && u < 3072) { pa[u] = 0; pb[u] = 0; pc[u] = 0; pd[u] = 0; }
        int v = t - 53072;
        if (v >= 0 && v < 65536) pooled[v] = 0;
        int w = t - 118608;
        if (w >= 0 && w < 512) gcnt[w] = 0;
    }
}

// ---------------------------------------------------------------------------
// CSR build (hierarchical scan: known-good ~6us)
// ---------------------------------------------------------------------------
__global__ void k_count_deg(const int* __restrict__ dst, int* __restrict__ deg, int E) {
    int e = blockIdx.x * blockDim.x + threadIdx.x;
    if (e < E) atomicAdd(&deg[dst[e]], 1);
}

__global__ void k_scan1(const int* __restrict__ deg, int* __restrict__ exg,
                        int* __restrict__ bsum, int n) {
    __shared__ int s[512];
    int tid = threadIdx.x;
    int i = blockIdx.x * 512 + tid;
    int v = (i < n) ? deg[i] : 0;
    s[tid] = v;
    __syncthreads();
    for (int off = 1; off < 512; off <<= 1) {
        int t = (tid >= off) ? s[tid - off] : 0;
        __syncthreads();
        s[tid] += t;
        __syncthreads();
    }
    if (i < n) exg[i] = s[tid] - v;
    if (tid == 511) bsum[blockIdx.x] = s[511];
}

__global__ void k_scan2(int* __restrict__ bsum, int nb) {
    __shared__ int s[128];
    int tid = threadIdx.x;
    int v = (tid < nb) ? bsum[tid] : 0;
    s[tid] = v;
    __syncthreads();
    for (int off = 1; off < 128; off <<= 1) {
        int t = (tid >= off) ? s[tid - off] : 0;
        __syncthreads();
        s[tid] += t;
        __syncthreads();
    }
    if (tid < nb) bsum[tid] = s[tid] - v;
}

__global__ void k_scan3(const int* __restrict__ exg, const int* __restrict__ bsum,
                        const int* __restrict__ deg,
                        int* __restrict__ rowptr, int* __restrict__ cursor,
                        float* __restrict__ inv_deg, int n, int E) {
    int i = blockIdx.x * blockDim.x + threadIdx.x;
    if (i < n) {
        int r = exg[i] + bsum[i >> 9];
        rowptr[i] = r;
        cursor[i] = r;
        int d = deg[i];
        inv_deg[i] = 1.0f / (float)max(d, 1);
        if (i == 0) rowptr[n] = E;
    }
}

__global__ void k_fill_csr(const int* __restrict__ src, const int* __restrict__ dst,
                           int* __restrict__ cursor, int* __restrict__ csr_src, int E) {
    int e = blockIdx.x * blockDim.x + threadIdx.x;
    if (e < E) {
        int pos = atomicAdd(&cursor[dst[e]], 1);
        csr_src[pos] = src[e];
    }
}

// ---------------------------------------------------------------------------
// Mean aggregation v7: row-major gather, 4-deep ILP (16 edges in flight).
// ---------------------------------------------------------------------------
__global__ void k_aggregate7(const unsigned short* __restrict__ xhi,
                             const int* __restrict__ csr_src, const int* __restrict__ rowptr,
                             const float* __restrict__ inv_deg,
                             unsigned short* __restrict__ ahi, unsigned short* __restrict__ alo) {
    int lane = threadIdx.x & 63;
    int wid = threadIdx.x >> 6;
    int node = blockIdx.x * 4 + wid;   // grid exact: 12500
    int beg = rowptr[node];
    int deg = rowptr[node + 1] - beg;
    int eg = lane >> 4;                // edge slot 0..3
    int fo = (lane & 15) * 8;          // feature offset (8 bf16 = 16B)

    int idx_l = (lane < deg) ? csr_src[beg + lane] : 0;

    float a0[8] = {0,0,0,0,0,0,0,0};
    float a1[8] = {0,0,0,0,0,0,0,0};
    float a2[8] = {0,0,0,0,0,0,0,0};
    float a3[8] = {0,0,0,0,0,0,0,0};
    int dmax = min(deg, 64);
    for (int base = 0; base < dmax; base += 16) {
        int s0 = __shfl(idx_l, base + eg);
        int s1 = __shfl(idx_l, base + 4 + eg);
        int s2 = __shfl(idx_l, base + 8 + eg);
        int s3 = __shfl(idx_l, base + 12 + eg);
        if (base + eg < deg) {
            u16x8 v = *(const u16x8*)(xhi + (size_t)s0 * 128 + fo);
            #pragma unroll
            for (int j = 0; j < 8; ++j) a0[j] += bf2f(v[j]);
        }
        if (base + 4 + eg < deg) {
            u16x8 v = *(const u16x8*)(xhi + (size_t)s1 * 128 + fo);
            #pragma unroll
            for (int j = 0; j < 8; ++j) a1[j] += bf2f(v[j]);
        }
        if (base + 8 + eg < deg) {
            u16x8 v = *(const u16x8*)(xhi + (size_t)s2 * 128 + fo);
            #pragma unroll
            for (int j = 0; j < 8; ++j) a2[j] += bf2f(v[j]);
        }
        if (base + 12 + eg < deg) {
            u16x8 v = *(const u16x8*)(xhi + (size_t)s3 * 128 + fo);
            #pragma unroll
            for (int j = 0; j < 8; ++j) a3[j] += bf2f(v[j]);
        }
    }
    // rare tail: deg > 64
    for (int e = beg + 64 + eg; e < beg + deg; e += 4) {
        int s = csr_src[e];
        u16x8 v = *(const u16x8*)(xhi + (size_t)s * 128 + fo);
        #pragma unroll
        for (int j = 0; j < 8; ++j) a0[j] += bf2f(v[j]);
    }

    #pragma unroll
    for (int j = 0; j < 8; ++j) {
        float a = (a0[j] + a1[j]) + (a2[j] + a3[j]);
        a += __shfl_xor(a, 16);
        a += __shfl_xor(a, 32);
        a0[j] = a;
    }
    if (lane < 16) {
        float idg = inv_deg[node];
        u16x8 hv, lv;
        #pragma unroll
        for (int j = 0; j < 8; ++j) {
            float a = a0[j] * idg;
            unsigned short h = f2bf(a);
            hv[j] = h;
            lv[j] = f2bf(a - bf2f(h));
        }
        *(u16x8*)(ahi + (size_t)node * 128 + fo) = hv;
        *(u16x8*)(alo + (size_t)node * 128 + fo) = lv;
    }
}

// ---------------------------------------------------------------------------
// MFMA GEMM + fused BN partials (391 blocks x 256 threads).
// ---------------------------------------------------------------------------
__launch_bounds__(256) __global__
void k_mfma_gemm(const unsigned short* __restrict__ Ahi0, const unsigned short* __restrict__ Alo0,
                 const unsigned short* __restrict__ Ahi1, const unsigned short* __restrict__ Alo1,
                 const unsigned short* __restrict__ Wpk, const float* __restrict__ bl,
                 float* __restrict__ Hout,
                 float* __restrict__ psum, float* __restrict__ pqsum) {
    int wid = threadIdx.x >> 6;
    int lane = threadIdx.x & 63;
    int m0 = blockIdx.x * 128 + wid * 32;
    int r = lane & 15;
    int kg = lane >> 4;

    f32x4 acc[2][8];
    #pragma unroll
    for (int nf = 0; nf < 8; ++nf) {
        float b = bl[nf * 16 + r];
        acc[0][nf] = f32x4{b, b, b, b};
        acc[1][nf] = f32x4{b, b, b, b};
    }

    #pragma unroll
    for (int ks = 0; ks < 8; ++ks) {
        const unsigned short* hi = (ks < 4) ? Ahi0 : Ahi1;
        const unsigned short* lo = (ks < 4) ? Alo0 : Alo1;
        int kc = (ks & 3) * 32 + kg * 8;
        bf16x8 ah0 = *(const bf16x8*)(hi + (size_t)(m0 + r) * 128 + kc);
        bf16x8 al0 = *(const bf16x8*)(lo + (size_t)(m0 + r) * 128 + kc);
        bf16x8 ah1 = *(const bf16x8*)(hi + (size_t)(m0 + 16 + r) * 128 + kc);
        bf16x8 al1 = *(const bf16x8*)(lo + (size_t)(m0 + 16 + r) * 128 + kc);
        const unsigned short* wb = Wpk + (size_t)ks * 8192;
        #pragma unroll
        for (int nf = 0; nf < 8; ++nf) {
            bf16x8 bh = *(const bf16x8*)(wb + (size_t)nf * 1024 + lane * 8);
            bf16x8 bl2 = *(const bf16x8*)(wb + (size_t)nf * 1024 + 512 + lane * 8);
            acc[0][nf] = __builtin_amdgcn_mfma_f32_16x16x32_bf16(ah0, bh,  acc[0][nf], 0, 0, 0);
            acc[0][nf] = __builtin_amdgcn_mfma_f32_16x16x32_bf16(al0, bh,  acc[0][nf], 0, 0, 0);
            acc[0][nf] = __builtin_amdgcn_mfma_f32_16x16x32_bf16(ah0, bl2, acc[0][nf], 0, 0, 0);
            acc[1][nf] = __builtin_amdgcn_mfma_f32_16x16x32_bf16(ah1, bh,  acc[1][nf], 0, 0, 0);
            acc[1][nf] = __builtin_amdgcn_mfma_f32_16x16x32_bf16(al1, bh,  acc[1][nf], 0, 0, 0);
            acc[1][nf] = __builtin_amdgcn_mfma_f32_16x16x32_bf16(ah1, bl2, acc[1][nf], 0, 0, 0);
        }
    }

    // C/D layout: col = lane&15, row = (lane>>4)*4 + reg
    #pragma unroll
    for (int mf = 0; mf < 2; ++mf)
        #pragma unroll
        for (int nf = 0; nf < 8; ++nf)
            #pragma unroll
            for (int g = 0; g < 4; ++g)
                Hout[(size_t)(m0 + mf * 16 + kg * 4 + g) * 128 + nf * 16 + r] = acc[mf][nf][g];

    // fused BN partial stats: per-column sum / sumsq over this block's 128 rows
    __shared__ float ls[4][8][16];
    __shared__ float lq[4][8][16];
    #pragma unroll
    for (int nf = 0; nf < 8; ++nf) {
        float ss = 0.f, qq = 0.f;
        #pragma unroll
        for (int mf = 0; mf < 2; ++mf)
            #pragma unroll
            for (int g = 0; g < 4; ++g) {
                int row = m0 + mf * 16 + kg * 4 + g;
                float v = acc[mf][nf][g];
                float msk = (row < NNODES) ? 1.f : 0.f;
                ss += v * msk;
                qq += v * v * msk;
            }
        ss += __shfl_xor(ss, 16);
        ss += __shfl_xor(ss, 32);
        qq += __shfl_xor(qq, 16);
        qq += __shfl_xor(qq, 32);
        if (lane < 16) { ls[wid][nf][lane] = ss; lq[wid][nf][lane] = qq; }
    }
    __syncthreads();
    int t = threadIdx.x;
    if (t < 128) {
        int nf = t >> 4, rr = t & 15;
        float ssum = ls[0][nf][rr] + ls[1][nf][rr] + ls[2][nf][rr] + ls[3][nf][rr];
        float qsum = lq[0][nf][rr] + lq[1][nf][rr] + lq[2][nf][rr] + lq[3][nf][rr];
        psum[(size_t)t * GEMMBLK + blockIdx.x] = ssum;
        pqsum[(size_t)t * GEMMBLK + blockIdx.x] = qsum;
    }
}

// ---------------------------------------------------------------------------
// BN finalize, parallel: one block per column, 64 lanes, wave reduce.
// ---------------------------------------------------------------------------
__global__ void k_bnfin2(const float* __restrict__ psum, const float* __restrict__ pqsum,
                         const float* __restrict__ gamma, const float* __restrict__ beta,
                         float* __restrict__ scale, float* __restrict__ shift) {
    int c = blockIdx.x;   // 128 blocks
    int t = threadIdx.x;  // 64
    float s = 0.f, q = 0.f;
    const float* ps = psum + (size_t)c * GEMMBLK;
    const float* pq = pqsum + (size_t)c * GEMMBLK;
    for (int b = t; b < GEMMBLK; b += 64) { s += ps[b]; q += pq[b]; }
    #pragma unroll
    for (int off = 32; off; off >>= 1) {
        s += __shfl_xor(s, off);
        q += __shfl_xor(q, off);
    }
    if (t == 0) {
        float inv_n = 1.0f / (float)NNODES;
        float mu = s * inv_n;
        float var = q * inv_n - mu * mu;
        float is = rsqrtf(var + BN_EPS);
        float g = gamma[c] * is;
        scale[c] = g;
        shift[c] = beta[c] - mu * g;
    }
}

// BN + ReLU, write next-layer activations as hi/lo bf16
__global__ void k_bnrelu2(const float* __restrict__ h, const float* __restrict__ scale,
                          const float* __restrict__ shift,
                          unsigned short* __restrict__ xhi, unsigned short* __restrict__ xlo) {
    int idx = blockIdx.x * 256 + threadIdx.x;   // float4 index; grid exact 6250
    int cv = idx & 31;
    float4 sc = ((const float4*)scale)[cv];
    float4 sh = ((const float4*)shift)[cv];
    float4 v = ((const float4*)h)[idx];
    v.x = fmaxf(v.x * sc.x + sh.x, 0.f);
    v.y = fmaxf(v.y * sc.y + sh.y, 0.f);
    v.z = fmaxf(v.z * sc.z + sh.z, 0.f);
    v.w = fmaxf(v.w * sc.w + sh.w, 0.f);
    ushort4 hh, ll;
    hh.x = f2bf(v.x); ll.x = f2bf(v.x - bf2f(hh.x));
    hh.y = f2bf(v.y); ll.y = f2bf(v.y - bf2f(hh.y));
    hh.z = f2bf(v.z); ll.z = f2bf(v.z - bf2f(hh.z));
    hh.w = f2bf(v.w); ll.w = f2bf(v.w - bf2f(hh.w));
    *(ushort4*)(xhi + (size_t)idx * 4) = hh;
    *(ushort4*)(xlo + (size_t)idx * 4) = ll;
}

// ---------------------------------------------------------------------------
// Segmented pooling (unchanged)
// ---------------------------------------------------------------------------
__global__ void k_pool_seg(const unsigned short* __restrict__ xhi,
                           const unsigned short* __restrict__ xlo,
                           const int* __restrict__ batch,
                           float* __restrict__ pooled, int* __restrict__ gcnt) {
    int t = threadIdx.x;           // 64
    int r0 = blockIdx.x * PROWS;   // grid 2000 exact
    float a0 = 0.f, a1 = 0.f;
    int cur = batch[r0];
    int seg = r0;
    for (int i = 0; i < PROWS; ++i) {
        int r = r0 + i;
        int g = batch[r];
        if (g != cur) {
            atomicAdd(&pooled[cur * 128 + 2 * t], a0);
            atomicAdd(&pooled[cur * 128 + 2 * t + 1], a1);
            if (t == 0) atomicAdd(&gcnt[cur], r - seg);
            a0 = a1 = 0.f; cur = g; seg = r;
        }
        unsigned uh = *(const unsigned*)(xhi + (size_t)r * 128 + 2 * t);
        unsigned ul = *(const unsigned*)(xlo + (size_t)r * 128 + 2 * t);
        a0 += bf2f((unsigned short)(uh & 0xffff)) + bf2f((unsigned short)(ul & 0xffff));
        a1 += bf2f((unsigned short)(uh >> 16)) + bf2f((unsigned short)(ul >> 16));
    }
    atomicAdd(&pooled[cur * 128 + 2 * t], a0);
    atomicAdd(&pooled[cur * 128 + 2 * t + 1], a1);
    if (t == 0) atomicAdd(&gcnt[cur], r0 + PROWS - seg);
}

// ---------------------------------------------------------------------------
// Classifier (unchanged)
// ---------------------------------------------------------------------------
__global__ void k_cls(const float* __restrict__ pooled, const int* __restrict__ gcnt,
                      const float* __restrict__ W1, const float* __restrict__ b1,
                      const float* __restrict__ W2, const float* __restrict__ b2,
                      float* __restrict__ out) {
    int g = blockIdx.x;
    int t = threadIdx.x;  // 64
    __shared__ float P[128];
    __shared__ float H1[64];
    float inv = 1.0f / (float)max(gcnt[g], 1);
    P[t] = pooled[g * 128 + t] * inv;
    P[t + 64] = pooled[g * 128 + 64 + t] * inv;
    __syncthreads();
    float a = b1[t];
    #pragma unroll 8
    for (int k = 0; k < 128; ++k) a += P[k] * W1[t * 128 + k];
    H1[t] = fmaxf(a, 0.f);
    __syncthreads();
    if (t < 10) {
        float a2 = b2[t];
        #pragma unroll 8
        for (int k = 0; k < 64; ++k) a2 += H1[k] * W2[t * 64 + k];
        out[g * 10 + t] = a2;
    }
}

// ---------------------------------------------------------------------------
// launch
// ---------------------------------------------------------------------------
extern "C" void kernel_launch(void* const* d_in, const int* in_sizes, int n_in,
                              void* d_out, int out_size, void* d_ws, size_t ws_size,
                              hipStream_t stream) {
    const float* x_in  = (const float*)d_in[0];
    const int*   ei    = (const int*)d_in[1];
    const int*   batch = (const int*)d_in[2];
    const float* Wl    = (const float*)d_in[3];
    const float* bl    = (const float*)d_in[4];
    const float* Wr    = (const float*)d_in[5];
    const float* gamma = (const float*)d_in[6];
    const float* beta  = (const float*)d_in[7];
    const float* W1    = (const float*)d_in[8];
    const float* b1    = (const float*)d_in[9];
    const float* W2    = (const float*)d_in[10];
    const float* b2    = (const float*)d_in[11];
    float* out = (float*)d_out;

    const int N = NNODES, E = NEDGES;
    const int* src = ei;
    const int* dst = ei + E;

    char* p = (char*)d_ws;
    auto alloc = [&](size_t bytes) {
        char* r = p;
        p += (bytes + 255) & ~(size_t)255;
        return r;
    };
    unsigned short* ahi = (unsigned short*)alloc((size_t)MPAD * HID * 2);
    unsigned short* alo = (unsigned short*)alloc((size_t)MPAD * HID * 2);
    unsigned short* xhi = (unsigned short*)alloc((size_t)MPAD * HID * 2);
    unsigned short* xlo = (unsigned short*)alloc((size_t)MPAD * HID * 2);
    float*  h        = (float*)alloc((size_t)MPAD * HID * 4);
    unsigned short* wpk = (unsigned short*)alloc((size_t)NLAYERS * 64 * 2 * 64 * 8 * 2);
    int*    deg      = (int*)alloc((size_t)N * 4);
    float*  inv_deg  = (float*)alloc((size_t)N * 4);
    int*    rowptr   = (int*)alloc((size_t)(N + 1) * 4);
    int*    cursor   = (int*)alloc((size_t)N * 4);
    int*    csr_src  = (int*)alloc((size_t)E * 4);
    int*    exg      = (int*)alloc((size_t)N * 4);
    int*    bsum     = (int*)alloc(512);
    float*  psum     = (float*)alloc((size_t)HID * GEMMBLK * 4);
    float*  pqsum    = (float*)alloc((size_t)HID * GEMMBLK * 4);
    float*  scale    = (float*)alloc(HID * 4);
    float*  shift    = (float*)alloc(HID * 4);
    float*  pooled   = (float*)alloc((size_t)NGRAPHS * HID * 4);
    int*    gcnt     = (int*)alloc((size_t)NGRAPHS * 4);

    // ---- prep: split + wpack + zero-init in one dispatch (6816 blocks) ----
    k_prep<<<6816, 256, 0, stream>>>(x_in, xhi, xlo, Wl, Wr, wpk, deg,
                                     (int*)(ahi + (size_t)N * HID), (int*)(alo + (size_t)N * HID),
                                     (int*)(xhi + (size_t)N * HID), (int*)(xlo + (size_t)N * HID),
                                     (int*)pooled, gcnt);

    // ---- CSR build: count -> hierarchical scan -> fill ----
    int eb = (E + 255) / 256;
    k_count_deg<<<eb, 256, 0, stream>>>(dst, deg, E);
    int nb = (N + 511) / 512;
    k_scan1<<<nb, 512, 0, stream>>>(deg, exg, bsum, N);
    k_scan2<<<1, 128, 0, stream>>>(bsum, nb);
    k_scan3<<<(N + 255) / 256, 256, 0, stream>>>(exg, bsum, deg, rowptr, cursor, inv_deg, N, E);
    k_fill_csr<<<eb, 256, 0, stream>>>(src, dst, cursor, csr_src, E);

    // ---- layers ----
    for (int l = 0; l < NLAYERS; ++l) {
        k_aggregate7<<<N / 4, 256, 0, stream>>>(xhi, csr_src, rowptr, inv_deg, ahi, alo);
        k_mfma_gemm<<<GEMMBLK, 256, 0, stream>>>(ahi, alo, xhi, xlo,
                                                 wpk + (size_t)l * 65536,
                                                 bl + (size_t)l * HID, h, psum, pqsum);
        k_bnfin2<<<HID, 64, 0, stream>>>(psum, pqsum, gamma + (size_t)l * HID,
                                         beta + (size_t)l * HID, scale, shift);
        k_bnrelu2<<<(N * HID / 4) / 256, 256, 0, stream>>>(h, scale, shift, xhi, xlo);
    }

    // ---- pool + classifier ----
    k_pool_seg<<<N / PROWS, 64, 0, stream>>>(xhi, xlo, batch, pooled, gcnt);
    k_cls<<<NGRAPHS, 64, 0, stream>>>(pooled, gcnt, W1, b1, W2, b2, out);
}